// Round 1
// baseline (58.003 us; speedup 1.0000x reference)
//
#include <hip/hip_runtime.h>

// Problem constants (from reference): H=64, EH=128, B=512, T=512
#define B_  512
#define T_  512
#define H_  64
#define EH_ 128   // 2*H
#define NW  8     // waves per block (512 threads)

__device__ __forceinline__ float wred_sum(float v) {
#pragma unroll
  for (int off = 32; off; off >>= 1) v += __shfl_xor(v, off, 64);
  return v;
}

__device__ __forceinline__ float sigm(float x) { return 1.0f / (1.0f + __expf(-x)); }

__global__ __launch_bounds__(512, 2)
void attn_decoder_fused(const float* __restrict__ h0, const float* __restrict__ c0,
                        const float* __restrict__ enc,
                        const float* __restrict__ Wa,  const float* __restrict__ ba,
                        const float* __restrict__ Wc,  const float* __restrict__ bc,
                        const float* __restrict__ wif, const float* __restrict__ whf,
                        const float* __restrict__ bif, const float* __restrict__ bhf,
                        const float* __restrict__ wir, const float* __restrict__ whr,
                        const float* __restrict__ bir, const float* __restrict__ bhr,
                        const int* __restrict__ dip,
                        float* __restrict__ out)
{
  const int b    = blockIdx.x;
  const int tid  = threadIdx.x;
  const int lane = tid & 63;
  const int wv   = tid >> 6;   // 0..7

  __shared__ float s_m[NW], s_l[NW];
  __shared__ float s_acc[NW][EH_];
  __shared__ float s_cat[2 * EH_];      // [enc[b,di,:], attn_applied]
  __shared__ float s_part[4][H_];
  __shared__ float s_comb[H_];
  __shared__ float s_h0[2 * H_];
  __shared__ float s_gates[2][4 * H_];

  const float* encb = enc + (size_t)b * T_ * EH_;

  // const_b = dec_hidden[b] . Wa[128:256] + ba   (dec_hidden = flat view of h0, row b)
  float2 dh = *(const float2*)(&h0[b * 2 * H_ + 2 * lane]);
  float2 w2 = *(const float2*)(&Wa[EH_ + 2 * lane]);
  const float cb = wred_sum(dh.x * w2.x + dh.y * w2.y) + ba[0];

  const float2 w1 = *(const float2*)(&Wa[2 * lane]);

  // online softmax over this wave's contiguous 64-t chunk
  float m = -1e30f, l = 0.0f, accx = 0.0f, accy = 0.0f;
  const int t0 = wv * (T_ / NW);

  for (int t = t0; t < t0 + T_ / NW; t += 8) {
    float2 e[8];
    float  s[8];
#pragma unroll
    for (int u = 0; u < 8; ++u)
      e[u] = *(const float2*)(&encb[(size_t)(t + u) * EH_ + 2 * lane]);
#pragma unroll
    for (int u = 0; u < 8; ++u)
      s[u] = e[u].x * w1.x + e[u].y * w1.y;
#pragma unroll
    for (int off = 32; off; off >>= 1)
#pragma unroll
      for (int u = 0; u < 8; ++u)
        s[u] += __shfl_xor(s[u], off, 64);

    float mx = cb + fmaxf(fmaxf(fmaxf(s[0], s[1]), fmaxf(s[2], s[3])),
                          fmaxf(fmaxf(s[4], s[5]), fmaxf(s[6], s[7])));
    float mnew  = fmaxf(m, mx);
    float scale = __expf(m - mnew);
    float p[8];
#pragma unroll
    for (int u = 0; u < 8; ++u) p[u] = __expf(s[u] + cb - mnew);
    float ps = 0.0f, ax = 0.0f, ay = 0.0f;
#pragma unroll
    for (int u = 0; u < 8; ++u) { ps += p[u]; ax += p[u] * e[u].x; ay += p[u] * e[u].y; }
    l    = l * scale + ps;
    accx = accx * scale + ax;
    accy = accy * scale + ay;
    m    = mnew;
  }

  s_acc[wv][2 * lane]     = accx;
  s_acc[wv][2 * lane + 1] = accy;
  if (lane == 0) { s_m[wv] = m; s_l[wv] = l; }
  __syncthreads();

  const int di = dip[0];

  // merge 8 partial softmax states; build out_cat in LDS
  if (tid < EH_) {
    float M = s_m[0];
#pragma unroll
    for (int w = 1; w < NW; ++w) M = fmaxf(M, s_m[w]);
    float L = 0.0f, a = 0.0f;
#pragma unroll
    for (int w = 0; w < NW; ++w) {
      float ew = __expf(s_m[w] - M);
      L += s_l[w] * ew;
      a += s_acc[w][tid] * ew;
    }
    s_cat[EH_ + tid] = a / L;                       // attn_applied
    s_cat[tid]       = encb[(size_t)di * EH_ + tid]; // enc[b, di, :]
  } else if (tid < 2 * EH_) {
    int j = tid - EH_;                               // 0..127
    s_h0[j] = h0[(j >> 6) * B_ * H_ + b * H_ + (j & 63)];
  }
  __syncthreads();

  // comb = relu(out_cat @ Wc^T + bc) : 64 outputs, 256-dot each, 4-way split
  if (tid < 256) {
    int k = tid & 63, part = tid >> 6;
    const float* wrow = Wc + k * 256 + part * 64;
    const float* cat  = s_cat + part * 64;
    float a = 0.0f;
#pragma unroll
    for (int j = 0; j < 64; ++j) a += cat[j] * wrow[j];
    s_part[part][k] = a;
  }
  __syncthreads();
  if (tid < H_) {
    float a = s_part[0][tid] + s_part[1][tid] + s_part[2][tid] + s_part[3][tid] + bc[tid];
    s_comb[tid] = fmaxf(a, 0.0f);
  }
  __syncthreads();

  // gates: 512 threads, one gate each: dir = tid>>8, g = tid&255
  {
    int dir = tid >> 8, g = tid & 255;
    const float* wih = dir ? wir : wif;
    const float* whh = dir ? whr : whf;
    const float* bih = dir ? bir : bif;
    const float* bhh = dir ? bhr : bhf;
    float a = bih[g] + bhh[g];
    const float* wi = wih + g * H_;
    const float* wh = whh + g * H_;
    const float* hh = s_h0 + dir * H_;
#pragma unroll
    for (int j = 0; j < H_; ++j) a += s_comb[j] * wi[j] + hh[j] * wh[j];
    s_gates[dir][g] = a;
  }
  __syncthreads();

  // finalize LSTM + write all three outputs
  if (tid < 2 * H_) {
    int dir = tid >> 6, j = tid & 63;
    float gi = s_gates[dir][j];
    float gf = s_gates[dir][H_ + j];
    float gg = s_gates[dir][2 * H_ + j];
    float go = s_gates[dir][3 * H_ + j];
    float cp = c0[dir * B_ * H_ + b * H_ + j];
    float cn = sigm(gf) * cp + sigm(gi) * tanhf(gg);
    float hn = sigm(go) * tanhf(cn);
    out[b * 2 * H_ + dir * H_ + j]              = hn;  // output (b,1,128)
    out[B_ * 2 * H_ + dir * B_ * H_ + b * H_ + j] = hn;  // h_new (2,b,64)
    out[2 * B_ * 2 * H_ + dir * B_ * H_ + b * H_ + j] = cn;  // c_new (2,b,64)
  }
}

extern "C" void kernel_launch(void* const* d_in, const int* in_sizes, int n_in,
                              void* d_out, int out_size, void* d_ws, size_t ws_size,
                              hipStream_t stream) {
  const float* h0  = (const float*)d_in[0];
  const float* c0  = (const float*)d_in[1];
  const float* enc = (const float*)d_in[2];
  const float* Wa  = (const float*)d_in[3];
  const float* ba  = (const float*)d_in[4];
  const float* Wc  = (const float*)d_in[5];
  const float* bc  = (const float*)d_in[6];
  const float* wif = (const float*)d_in[7];
  const float* whf = (const float*)d_in[8];
  const float* bif = (const float*)d_in[9];
  const float* bhf = (const float*)d_in[10];
  const float* wir = (const float*)d_in[11];
  const float* whr = (const float*)d_in[12];
  const float* bir = (const float*)d_in[13];
  const float* bhr = (const float*)d_in[14];
  const int*   dip = (const int*)d_in[15];
  float* out = (float*)d_out;

  attn_decoder_fused<<<B_, 512, 0, stream>>>(h0, c0, enc, Wa, ba, Wc, bc,
                                             wif, whf, bif, bhf,
                                             wir, whr, bir, bhr, dip, out);
}